// Round 1
// baseline (536.705 us; speedup 1.0000x reference)
//
#include <hip/hip_runtime.h>
#include <cstdint>
#include <cstddef>

// Problem dims (fixed by the reference: B=8, S=2048, DIN=1152, DOUT=4608)
#define M_DIM 16384   // B*S
#define N_DIM 4608    // DOUT
#define K_DIM 1152    // DIN

typedef __attribute__((ext_vector_type(8))) __bf16 bf16x8;
typedef __attribute__((ext_vector_type(4))) float  f32x4;

__device__ __forceinline__ unsigned short f2bf(float f) {
    // round-to-nearest-even fp32 -> bf16 (no NaN handling needed for this data)
    unsigned int u = __float_as_uint(f);
    unsigned int r = (u + 0x7FFFu + ((u >> 16) & 1u)) >> 16;
    return (unsigned short)r;
}

__device__ __forceinline__ float gelu_tanh_f(float v) {
    // 0.5*v*(1+tanh(c0*(v + c1*v^3))), stable tanh via exp(-2|u|)
    float u = 0.7978845608028654f * (v + 0.044715f * v * v * v);
    float a = fabsf(u);
    float t = __expf(-2.0f * a);
    float th = (1.0f - t) / (1.0f + t);
    th = (u < 0.0f) ? -th : th;
    return 0.5f * v * (1.0f + th);
}

// ---------------- prepass: dtype conversion into workspace ----------------

__global__ void cvt_f32_bf16(const float* __restrict__ in,
                             unsigned short* __restrict__ out, int n4) {
    int i = blockIdx.x * 256 + threadIdx.x;
    if (i >= n4) return;
    float4 v = ((const float4*)in)[i];
    ushort4 o;
    o.x = f2bf(v.x); o.y = f2bf(v.y); o.z = f2bf(v.z); o.w = f2bf(v.w);
    ((ushort4*)out)[i] = o;
}

__global__ void cvt_i32_bf16(const int* __restrict__ in,
                             unsigned short* __restrict__ out, int n4) {
    int i = blockIdx.x * 256 + threadIdx.x;
    if (i >= n4) return;
    int4 v = ((const int4*)in)[i];
    ushort4 o;
    o.x = f2bf((float)v.x); o.y = f2bf((float)v.y);
    o.z = f2bf((float)v.z); o.w = f2bf((float)v.w);
    ((ushort4*)out)[i] = o;
}

// ---------------- fused GEMM + scale + bias + gelu ----------------
//
// Tile: BM=BN=128, BK=64. 256 threads = 4 waves, each wave owns a 64x64
// sub-tile as 4x4 grid of 16x16 MFMA accumulators.
// LDS layout: [row][64 bf16] with 16B-chunk XOR swizzle (chunk ^= row&7)
// so global_load_lds (wave-uniform base + lane*16, no padding allowed) and
// conflict-free ds_read_b128 coexist.

template <bool PRE>
__global__ void qgelu_gemm(const void* __restrict__ Aptr,
                           const void* __restrict__ Wptr,
                           const float* __restrict__ w_scale,
                           const float* __restrict__ bias,
                           float* __restrict__ out) {
    __shared__ __align__(16) unsigned short As[128 * 64];
    __shared__ __align__(16) unsigned short Bs[128 * 64];

    const int tid    = threadIdx.x;
    const int l      = tid & 63;
    const int wv     = tid >> 6;
    const int lane16 = l & 15;
    const int quad   = l >> 4;
    const int m0 = blockIdx.x * 128;
    const int n0 = blockIdx.y * 128;
    const int wm = (wv & 1) * 64;
    const int wn = (wv >> 1) * 64;

    f32x4 acc[4][4];
#pragma unroll
    for (int i = 0; i < 4; ++i)
#pragma unroll
        for (int j = 0; j < 4; ++j) acc[i][j] = f32x4{0.f, 0.f, 0.f, 0.f};

    const unsigned short* Abf = (const unsigned short*)Aptr;
    const unsigned short* Wbf = (const unsigned short*)Wptr;
    const float* Af = (const float*)Aptr;
    const int*   Wi = (const int*)Wptr;

    for (int kt = 0; kt < K_DIM / 64; ++kt) {
        __syncthreads();  // previous compute done before overwriting LDS
        if constexpr (PRE) {
#pragma unroll
            for (int i = 0; i < 4; ++i) {
                int q   = wv * 64 + i * 256 + l;  // 16B-chunk index 0..1023
                int row = q >> 3;                 // 0..127
                int p   = q & 7;                  // LDS chunk slot in row
                int c   = p ^ (row & 7);          // global chunk (swizzle)
                const unsigned short* ga =
                    Abf + (size_t)(m0 + row) * K_DIM + kt * 64 + c * 8;
                const unsigned short* gb =
                    Wbf + (size_t)(n0 + row) * K_DIM + kt * 64 + c * 8;
                unsigned short* la = &As[(wv * 64 + i * 256) * 8];
                unsigned short* lb = &Bs[(wv * 64 + i * 256) * 8];
                __builtin_amdgcn_global_load_lds(
                    (const __attribute__((address_space(1))) unsigned int*)ga,
                    (__attribute__((address_space(3))) unsigned int*)la, 16, 0, 0);
                __builtin_amdgcn_global_load_lds(
                    (const __attribute__((address_space(1))) unsigned int*)gb,
                    (__attribute__((address_space(3))) unsigned int*)lb, 16, 0, 0);
            }
        } else {
            // fused-conversion fallback (no workspace): fp32/int32 -> bf16 in regs
#pragma unroll
            for (int i = 0; i < 8; ++i) {
                int g    = i * 256 + tid;   // 4-elem group 0..2047
                int row  = g >> 4;
                int grp  = g & 15;          // 4-elem group within row
                int c    = grp >> 1;        // global 16B chunk
                int half = g & 1;
                int p    = c ^ (row & 7);   // swizzled LDS chunk slot
                int off  = row * 64 + p * 8 + half * 4;  // ushort units
                {
                    float4 v = *(const float4*)(Af + (size_t)(m0 + row) * K_DIM +
                                                kt * 64 + grp * 4);
                    ushort4 o;
                    o.x = f2bf(v.x); o.y = f2bf(v.y);
                    o.z = f2bf(v.z); o.w = f2bf(v.w);
                    *(ushort4*)(As + off) = o;
                }
                {
                    int4 v = *(const int4*)(Wi + (size_t)(n0 + row) * K_DIM +
                                            kt * 64 + grp * 4);
                    ushort4 o;
                    o.x = f2bf((float)v.x); o.y = f2bf((float)v.y);
                    o.z = f2bf((float)v.z); o.w = f2bf((float)v.w);
                    *(ushort4*)(Bs + off) = o;
                }
            }
        }
        __syncthreads();

#pragma unroll
        for (int s = 0; s < 2; ++s) {  // two k-steps of 32 within BK=64
            bf16x8 af[4], bfr[4];
#pragma unroll
            for (int mt = 0; mt < 4; ++mt) {
                int row = wm + mt * 16 + lane16;
                int p   = (s * 4 + quad) ^ (row & 7);
                af[mt]  = *(const bf16x8*)(As + row * 64 + p * 8);
            }
#pragma unroll
            for (int nt = 0; nt < 4; ++nt) {
                int row = wn + nt * 16 + lane16;
                int p   = (s * 4 + quad) ^ (row & 7);
                bfr[nt] = *(const bf16x8*)(Bs + row * 64 + p * 8);
            }
#pragma unroll
            for (int mt = 0; mt < 4; ++mt)
#pragma unroll
                for (int nt = 0; nt < 4; ++nt)
                    acc[mt][nt] = __builtin_amdgcn_mfma_f32_16x16x32_bf16(
                        af[mt], bfr[nt], acc[mt][nt], 0, 0, 0);
        }
    }

    // epilogue: per-output-channel scale + bias + gelu, direct stores
    // C/D layout (verified m89/m91): col = lane&15, row = quad*4 + reg
#pragma unroll
    for (int nt = 0; nt < 4; ++nt) {
        int n    = n0 + wn + nt * 16 + lane16;
        float sc = w_scale[n];
        float bi = bias[n];
#pragma unroll
        for (int mt = 0; mt < 4; ++mt) {
#pragma unroll
            for (int r = 0; r < 4; ++r) {
                int m   = m0 + wm + mt * 16 + quad * 4 + r;
                float v = acc[mt][nt][r] * sc + bi;
                out[(size_t)m * N_DIM + n] = gelu_tanh_f(v);
            }
        }
    }
}

extern "C" void kernel_launch(void* const* d_in, const int* in_sizes, int n_in,
                              void* d_out, int out_size, void* d_ws, size_t ws_size,
                              hipStream_t stream) {
    const float* hs   = (const float*)d_in[0];  // [8,2048,1152] fp32
    const int*   w8   = (const int*)d_in[1];    // [4608,1152] int32 (int8 values)
    const float* wsc  = (const float*)d_in[2];  // [4608]
    const float* bias = (const float*)d_in[3];  // [4608]
    float* out = (float*)d_out;                 // [8,2048,4608] fp32

    const size_t nA = (size_t)M_DIM * K_DIM;  // bf16 elems
    const size_t nW = (size_t)N_DIM * K_DIM;
    const size_t need = (nA + nW) * sizeof(unsigned short);

    dim3 grid(M_DIM / 128, N_DIM / 128);  // x = m-tiles (consecutive blocks share W slab)

    if (ws_size >= need) {
        unsigned short* Abf = (unsigned short*)d_ws;
        unsigned short* Wbf = Abf + nA;
        int a4 = (int)(nA / 4), w4 = (int)(nW / 4);
        cvt_f32_bf16<<<(a4 + 255) / 256, 256, 0, stream>>>(hs, Abf, a4);
        cvt_i32_bf16<<<(w4 + 255) / 256, 256, 0, stream>>>(w8, Wbf, w4);
        qgelu_gemm<true><<<grid, 256, 0, stream>>>(Abf, Wbf, wsc, bias, out);
    } else {
        qgelu_gemm<false><<<grid, 256, 0, stream>>>(hs, w8, wsc, bias, out);
    }
}

// Round 2
// 509.352 us; speedup vs baseline: 1.0537x; 1.0537x over previous
//
#include <hip/hip_runtime.h>
#include <cstdint>
#include <cstddef>

// Problem dims (fixed by the reference: B=8, S=2048, DIN=1152, DOUT=4608)
#define M_DIM 16384   // B*S
#define N_DIM 4608    // DOUT
#define K_DIM 1152    // DIN

typedef __attribute__((ext_vector_type(8))) __bf16 bf16x8;
typedef __attribute__((ext_vector_type(4))) float  f32x4;
typedef __attribute__((ext_vector_type(4))) int    v4i;

__device__ __forceinline__ unsigned short f2bf(float f) {
    unsigned int u = __float_as_uint(f);
    unsigned int r = (u + 0x7FFFu + ((u >> 16) & 1u)) >> 16;
    return (unsigned short)r;
}

__device__ __forceinline__ float gelu_tanh_f(float v) {
    // 0.5*v*(1+tanh(c0*(v + c1*v^3))), stable tanh via exp(-2|u|)
    float u = 0.7978845608028654f * (v + 0.044715f * v * v * v);
    float a = fabsf(u);
    float t = __expf(-2.0f * a);
    float th = (1.0f - t) / (1.0f + t);
    th = (u < 0.0f) ? -th : th;
    return 0.5f * v * (1.0f + th);
}

// ---------------- prepass 1: per-row dynamic int8 quantization of A --------
// One wave per row (1152 floats = 576 float2 = 9 float2/lane). RNE quant.
__global__ void quant_rows(const float* __restrict__ A,
                           signed char* __restrict__ qa,
                           float* __restrict__ sA) {
    const int lane = threadIdx.x & 63;
    const int row  = blockIdx.x * 4 + (threadIdx.x >> 6);
    const float2* src = (const float2*)(A + (size_t)row * K_DIM);
    float2 v[9];
    float amax = 0.f;
#pragma unroll
    for (int j = 0; j < 9; ++j) {
        v[j] = src[j * 64 + lane];
        amax = fmaxf(amax, fmaxf(fabsf(v[j].x), fabsf(v[j].y)));
    }
#pragma unroll
    for (int off = 32; off > 0; off >>= 1)
        amax = fmaxf(amax, __shfl_xor(amax, off));
    amax = fmaxf(amax, 1e-30f);
    float inv = 127.0f / amax;
    if (lane == 0) sA[row] = amax * (1.0f / 127.0f);
    char2* dst = (char2*)(qa + (size_t)row * K_DIM);
#pragma unroll
    for (int j = 0; j < 9; ++j) {
        char2 o;
        o.x = (signed char)__float2int_rn(v[j].x * inv);
        o.y = (signed char)__float2int_rn(v[j].y * inv);
        dst[j * 64 + lane] = o;
    }
}

// ---------------- prepass 2: pack int32 weights -> int8 (exact) ------------
__global__ void pack_w(const int* __restrict__ w,
                       signed char* __restrict__ qw, int n4) {
    int i = blockIdx.x * 256 + threadIdx.x;
    if (i >= n4) return;
    int4 v = ((const int4*)w)[i];
    char4 o;
    o.x = (signed char)v.x; o.y = (signed char)v.y;
    o.z = (signed char)v.z; o.w = (signed char)v.w;
    ((char4*)qw)[i] = o;
}

// ---------------- i8 GEMM + scale + bias + gelu ----------------------------
// Tile BM=BN=128, BK=128 (int8 bytes). 256 threads = 4 waves, each wave a
// 64x64 sub-tile = 4x4 grid of 16x16 accumulators, mfma_i32_16x16x64_i8.
// LDS rows are 128 B = 8x16B chunks; XOR swizzle chunk^=(row&7) keeps
// global_load_lds's lane*16 layout AND conflict-free ds_read_b128
// (16 lanes/quad spread over 8 chunk cols -> 2 lanes/bank = free, m136).
__global__ void qgelu_gemm_i8(const signed char* __restrict__ Aq,
                              const signed char* __restrict__ Wq,
                              const float* __restrict__ sA,
                              const float* __restrict__ w_scale,
                              const float* __restrict__ bias,
                              float* __restrict__ out) {
    __shared__ __align__(16) signed char As[128 * 128];
    __shared__ __align__(16) signed char Bs[128 * 128];

    const int tid    = threadIdx.x;
    const int l      = tid & 63;
    const int wv     = tid >> 6;
    const int lane16 = l & 15;
    const int quad   = l >> 4;
    const int m0 = blockIdx.x * 128;
    const int n0 = blockIdx.y * 128;
    const int wm = (wv & 1) * 64;
    const int wn = (wv >> 1) * 64;

    v4i acc[4][4];
#pragma unroll
    for (int i = 0; i < 4; ++i)
#pragma unroll
        for (int j = 0; j < 4; ++j) acc[i][j] = v4i{0, 0, 0, 0};

    for (int kt = 0; kt < K_DIM / 128; ++kt) {
        __syncthreads();  // previous compute done before overwriting LDS
#pragma unroll
        for (int i = 0; i < 4; ++i) {
            int q   = wv * 64 + i * 256 + l;  // 16B-chunk index 0..1023
            int row = q >> 3;                 // 0..127
            int p   = q & 7;                  // LDS chunk slot in row
            int c   = p ^ (row & 7);          // global chunk (swizzle)
            const signed char* ga = Aq + (size_t)(m0 + row) * K_DIM + kt * 128 + c * 16;
            const signed char* gb = Wq + (size_t)(n0 + row) * K_DIM + kt * 128 + c * 16;
            signed char* la = As + (size_t)(wv * 64 + i * 256) * 16;
            signed char* lb = Bs + (size_t)(wv * 64 + i * 256) * 16;
            __builtin_amdgcn_global_load_lds(
                (const __attribute__((address_space(1))) unsigned int*)ga,
                (__attribute__((address_space(3))) unsigned int*)la, 16, 0, 0);
            __builtin_amdgcn_global_load_lds(
                (const __attribute__((address_space(1))) unsigned int*)gb,
                (__attribute__((address_space(3))) unsigned int*)lb, 16, 0, 0);
        }
        __syncthreads();

#pragma unroll
        for (int s = 0; s < 2; ++s) {  // two k-steps of 64 within BK=128
            v4i af[4], bfr[4];
#pragma unroll
            for (int mt = 0; mt < 4; ++mt) {
                int row = wm + mt * 16 + lane16;
                int p   = (s * 4 + quad) ^ (row & 7);
                af[mt]  = *(const v4i*)(As + row * 128 + p * 16);
            }
#pragma unroll
            for (int nt = 0; nt < 4; ++nt) {
                int row = wn + nt * 16 + lane16;
                int p   = (s * 4 + quad) ^ (row & 7);
                bfr[nt] = *(const v4i*)(Bs + row * 128 + p * 16);
            }
#pragma unroll
            for (int mt = 0; mt < 4; ++mt)
#pragma unroll
                for (int nt = 0; nt < 4; ++nt)
                    acc[mt][nt] = __builtin_amdgcn_mfma_i32_16x16x64_i8(
                        af[mt], bfr[nt], acc[mt][nt], 0, 0, 0);
        }
    }

    // epilogue: v = sA[m] * acc * w_scale[n] + bias[n] -> gelu
    // C/D layout (m89/m91, dtype-independent): col=lane&15, row=quad*4+reg
#pragma unroll
    for (int nt = 0; nt < 4; ++nt) {
        int n    = n0 + wn + nt * 16 + lane16;
        float sc = w_scale[n];
        float bi = bias[n];
#pragma unroll
        for (int mt = 0; mt < 4; ++mt) {
            int mbase = m0 + wm + mt * 16 + quad * 4;
#pragma unroll
            for (int r = 0; r < 4; ++r) {
                float v = (float)acc[mt][nt][r] * sA[mbase + r] * sc + bi;
                out[(size_t)(mbase + r) * N_DIM + n] = gelu_tanh_f(v);
            }
        }
    }
}

// ---------------- bf16 fused fallback (if ws too small) --------------------
__global__ void qgelu_gemm_bf16_fused(const float* __restrict__ Af,
                                      const int* __restrict__ Wi,
                                      const float* __restrict__ w_scale,
                                      const float* __restrict__ bias,
                                      float* __restrict__ out) {
    __shared__ __align__(16) unsigned short As[128 * 64];
    __shared__ __align__(16) unsigned short Bs[128 * 64];

    const int tid    = threadIdx.x;
    const int l      = tid & 63;
    const int wv     = tid >> 6;
    const int lane16 = l & 15;
    const int quad   = l >> 4;
    const int m0 = blockIdx.x * 128;
    const int n0 = blockIdx.y * 128;
    const int wm = (wv & 1) * 64;
    const int wn = (wv >> 1) * 64;

    f32x4 acc[4][4];
#pragma unroll
    for (int i = 0; i < 4; ++i)
#pragma unroll
        for (int j = 0; j < 4; ++j) acc[i][j] = f32x4{0.f, 0.f, 0.f, 0.f};

    for (int kt = 0; kt < K_DIM / 64; ++kt) {
        __syncthreads();
#pragma unroll
        for (int i = 0; i < 8; ++i) {
            int g    = i * 256 + tid;
            int row  = g >> 4;
            int grp  = g & 15;
            int c    = grp >> 1;
            int half = g & 1;
            int p    = c ^ (row & 7);
            int off  = row * 64 + p * 8 + half * 4;
            {
                float4 v = *(const float4*)(Af + (size_t)(m0 + row) * K_DIM + kt * 64 + grp * 4);
                ushort4 o;
                o.x = f2bf(v.x); o.y = f2bf(v.y); o.z = f2bf(v.z); o.w = f2bf(v.w);
                *(ushort4*)(As + off) = o;
            }
            {
                int4 v = *(const int4*)(Wi + (size_t)(n0 + row) * K_DIM + kt * 64 + grp * 4);
                ushort4 o;
                o.x = f2bf((float)v.x); o.y = f2bf((float)v.y);
                o.z = f2bf((float)v.z); o.w = f2bf((float)v.w);
                *(ushort4*)(Bs + off) = o;
            }
        }
        __syncthreads();

#pragma unroll
        for (int s = 0; s < 2; ++s) {
            bf16x8 af[4], bfr[4];
#pragma unroll
            for (int mt = 0; mt < 4; ++mt) {
                int row = wm + mt * 16 + lane16;
                int p   = (s * 4 + quad) ^ (row & 7);
                af[mt]  = *(const bf16x8*)(As + row * 64 + p * 8);
            }
#pragma unroll
            for (int nt = 0; nt < 4; ++nt) {
                int row = wn + nt * 16 + lane16;
                int p   = (s * 4 + quad) ^ (row & 7);
                bfr[nt] = *(const bf16x8*)(Bs + row * 64 + p * 8);
            }
#pragma unroll
            for (int mt = 0; mt < 4; ++mt)
#pragma unroll
                for (int nt = 0; nt < 4; ++nt)
                    acc[mt][nt] = __builtin_amdgcn_mfma_f32_16x16x32_bf16(
                        af[mt], bfr[nt], acc[mt][nt], 0, 0, 0);
        }
    }

#pragma unroll
    for (int nt = 0; nt < 4; ++nt) {
        int n    = n0 + wn + nt * 16 + lane16;
        float sc = w_scale[n];
        float bi = bias[n];
#pragma unroll
        for (int mt = 0; mt < 4; ++mt) {
#pragma unroll
            for (int r = 0; r < 4; ++r) {
                int m   = m0 + wm + mt * 16 + quad * 4 + r;
                float v = acc[mt][nt][r] * sc + bi;
                out[(size_t)m * N_DIM + n] = gelu_tanh_f(v);
            }
        }
    }
}

extern "C" void kernel_launch(void* const* d_in, const int* in_sizes, int n_in,
                              void* d_out, int out_size, void* d_ws, size_t ws_size,
                              hipStream_t stream) {
    const float* hs   = (const float*)d_in[0];  // [8,2048,1152] fp32
    const int*   w8   = (const int*)d_in[1];    // [4608,1152] int32 (int8 values)
    const float* wsc  = (const float*)d_in[2];  // [4608]
    const float* bias = (const float*)d_in[3];  // [4608]
    float* out = (float*)d_out;                 // [8,2048,4608] fp32

    const size_t nA = (size_t)M_DIM * K_DIM;  // int8 elems
    const size_t nW = (size_t)N_DIM * K_DIM;
    const size_t need = nA + nW + (size_t)M_DIM * sizeof(float);

    dim3 grid(M_DIM / 128, N_DIM / 128);

    if (ws_size >= need) {
        signed char* qa = (signed char*)d_ws;
        signed char* qw = qa + nA;
        float* sA = (float*)(qa + nA + nW);  // 16B-aligned (nA+nW % 16 == 0)
        quant_rows<<<M_DIM / 4, 256, 0, stream>>>(hs, qa, sA);
        int w4 = (int)(nW / 4);
        pack_w<<<(w4 + 255) / 256, 256, 0, stream>>>(w8, qw, w4);
        qgelu_gemm_i8<<<grid, 256, 0, stream>>>(qa, qw, sA, wsc, bias, out);
    } else {
        qgelu_gemm_bf16_fused<<<grid, 256, 0, stream>>>(hs, w8, wsc, bias, out);
    }
}

// Round 3
// 455.122 us; speedup vs baseline: 1.1793x; 1.1192x over previous
//
#include <hip/hip_runtime.h>
#include <cstdint>
#include <cstddef>

// Problem dims (fixed by the reference: B=8, S=2048, DIN=1152, DOUT=4608)
#define M_DIM 16384   // B*S
#define N_DIM 4608    // DOUT
#define K_DIM 1152    // DIN

typedef __attribute__((ext_vector_type(8))) __bf16 bf16x8;
typedef __attribute__((ext_vector_type(4))) float  f32x4;
typedef __attribute__((ext_vector_type(4))) int    v4i;

__device__ __forceinline__ unsigned short f2bf(float f) {
    unsigned int u = __float_as_uint(f);
    unsigned int r = (u + 0x7FFFu + ((u >> 16) & 1u)) >> 16;
    return (unsigned short)r;
}

__device__ __forceinline__ float gelu_tanh_f(float v) {
    // 0.5*v*(1+tanh(c0*(v + c1*v^3))), stable tanh via exp(-2|u|)
    float u = 0.7978845608028654f * (v + 0.044715f * v * v * v);
    float a = fabsf(u);
    float t = __expf(-2.0f * a);
    float th = (1.0f - t) / (1.0f + t);
    th = (u < 0.0f) ? -th : th;
    return 0.5f * v * (1.0f + th);
}

// ---------------- merged prepass ----------------
// Blocks [0, M_DIM/4): per-row dynamic int8 quantization of A (1 wave/row).
// Blocks [M_DIM/4, ...): pack int32 weights -> int8 (exact).
#define QA_BLOCKS (M_DIM / 4)
#define W4_COUNT  ((N_DIM * K_DIM) / 4)
#define PW_BLOCKS ((W4_COUNT + 255) / 256)

__global__ void prepass(const float* __restrict__ A,
                        const int* __restrict__ w,
                        signed char* __restrict__ qa,
                        float* __restrict__ sA,
                        signed char* __restrict__ qw) {
    if (blockIdx.x < QA_BLOCKS) {
        const int lane = threadIdx.x & 63;
        const int row  = blockIdx.x * 4 + (threadIdx.x >> 6);
        const float2* src = (const float2*)(A + (size_t)row * K_DIM);
        float2 v[9];
        float amax = 0.f;
#pragma unroll
        for (int j = 0; j < 9; ++j) {
            v[j] = src[j * 64 + lane];
            amax = fmaxf(amax, fmaxf(fabsf(v[j].x), fabsf(v[j].y)));
        }
#pragma unroll
        for (int off = 32; off > 0; off >>= 1)
            amax = fmaxf(amax, __shfl_xor(amax, off));
        amax = fmaxf(amax, 1e-30f);
        float inv = 127.0f / amax;
        if (lane == 0) sA[row] = amax * (1.0f / 127.0f);
        char2* dst = (char2*)(qa + (size_t)row * K_DIM);
#pragma unroll
        for (int j = 0; j < 9; ++j) {
            char2 o;
            o.x = (signed char)__float2int_rn(v[j].x * inv);
            o.y = (signed char)__float2int_rn(v[j].y * inv);
            dst[j * 64 + lane] = o;
        }
    } else {
        int i = (blockIdx.x - QA_BLOCKS) * 256 + threadIdx.x;
        if (i >= W4_COUNT) return;
        int4 v = ((const int4*)w)[i];
        char4 o;
        o.x = (signed char)v.x; o.y = (signed char)v.y;
        o.z = (signed char)v.z; o.w = (signed char)v.w;
        ((char4*)qw)[i] = o;
    }
}

// ---------------- i8 GEMM + scale + bias + gelu ----------------------------
// Tile BM=BN=128, BK=128 (int8 bytes). 256 threads = 4 waves, each wave a
// 64x64 sub-tile = 4x4 grid of 16x16 accumulators, mfma_i32_16x16x64_i8.
// LDS rows are 128 B = 8x16B chunks; XOR swizzle chunk^=(row&7) keeps
// global_load_lds's lane*16 layout AND conflict-free ds_read_b128.
// Output stores are NON-TEMPORAL: write-once stream must not evict the
// A/W slabs (19+5.3 MB) from L3 — they're re-read 36x/128x by other blocks.
__global__ void qgelu_gemm_i8(const signed char* __restrict__ Aq,
                              const signed char* __restrict__ Wq,
                              const float* __restrict__ sA,
                              const float* __restrict__ w_scale,
                              const float* __restrict__ bias,
                              float* __restrict__ out) {
    __shared__ __align__(16) signed char As[128 * 128];
    __shared__ __align__(16) signed char Bs[128 * 128];

    const int tid    = threadIdx.x;
    const int l      = tid & 63;
    const int wv     = tid >> 6;
    const int lane16 = l & 15;
    const int quad   = l >> 4;
    const int m0 = blockIdx.x * 128;
    const int n0 = blockIdx.y * 128;
    const int wm = (wv & 1) * 64;
    const int wn = (wv >> 1) * 64;

    v4i acc[4][4];
#pragma unroll
    for (int i = 0; i < 4; ++i)
#pragma unroll
        for (int j = 0; j < 4; ++j) acc[i][j] = v4i{0, 0, 0, 0};

    for (int kt = 0; kt < K_DIM / 128; ++kt) {
        __syncthreads();  // previous compute done before overwriting LDS
#pragma unroll
        for (int i = 0; i < 4; ++i) {
            int q   = wv * 64 + i * 256 + l;  // 16B-chunk index 0..1023
            int row = q >> 3;                 // 0..127
            int p   = q & 7;                  // LDS chunk slot in row
            int c   = p ^ (row & 7);          // global chunk (swizzle)
            const signed char* ga = Aq + (size_t)(m0 + row) * K_DIM + kt * 128 + c * 16;
            const signed char* gb = Wq + (size_t)(n0 + row) * K_DIM + kt * 128 + c * 16;
            signed char* la = As + (size_t)(wv * 64 + i * 256) * 16;
            signed char* lb = Bs + (size_t)(wv * 64 + i * 256) * 16;
            __builtin_amdgcn_global_load_lds(
                (const __attribute__((address_space(1))) unsigned int*)ga,
                (__attribute__((address_space(3))) unsigned int*)la, 16, 0, 0);
            __builtin_amdgcn_global_load_lds(
                (const __attribute__((address_space(1))) unsigned int*)gb,
                (__attribute__((address_space(3))) unsigned int*)lb, 16, 0, 0);
        }
        __syncthreads();

#pragma unroll
        for (int s = 0; s < 2; ++s) {  // two k-steps of 64 within BK=128
            v4i af[4], bfr[4];
#pragma unroll
            for (int mt = 0; mt < 4; ++mt) {
                int row = wm + mt * 16 + lane16;
                int p   = (s * 4 + quad) ^ (row & 7);
                af[mt]  = *(const v4i*)(As + row * 128 + p * 16);
            }
#pragma unroll
            for (int nt = 0; nt < 4; ++nt) {
                int row = wn + nt * 16 + lane16;
                int p   = (s * 4 + quad) ^ (row & 7);
                bfr[nt] = *(const v4i*)(Bs + row * 128 + p * 16);
            }
#pragma unroll
            for (int mt = 0; mt < 4; ++mt)
#pragma unroll
                for (int nt = 0; nt < 4; ++nt)
                    acc[mt][nt] = __builtin_amdgcn_mfma_i32_16x16x64_i8(
                        af[mt], bfr[nt], acc[mt][nt], 0, 0, 0);
        }
    }

    // epilogue: v = sA[m] * acc * w_scale[n] + bias[n] -> gelu -> nt store
    // C/D layout (m89/m91, dtype-independent): col=lane&15, row=quad*4+reg
#pragma unroll
    for (int nt = 0; nt < 4; ++nt) {
        int n    = n0 + wn + nt * 16 + lane16;
        float sc = w_scale[n];
        float bi = bias[n];
#pragma unroll
        for (int mt = 0; mt < 4; ++mt) {
            int mbase = m0 + wm + mt * 16 + quad * 4;
#pragma unroll
            for (int r = 0; r < 4; ++r) {
                float v = (float)acc[mt][nt][r] * sA[mbase + r] * sc + bi;
                __builtin_nontemporal_store(
                    gelu_tanh_f(v), &out[(size_t)(mbase + r) * N_DIM + n]);
            }
        }
    }
}

// ---------------- bf16 fused fallback (if ws too small) --------------------
__global__ void qgelu_gemm_bf16_fused(const float* __restrict__ Af,
                                      const int* __restrict__ Wi,
                                      const float* __restrict__ w_scale,
                                      const float* __restrict__ bias,
                                      float* __restrict__ out) {
    __shared__ __align__(16) unsigned short As[128 * 64];
    __shared__ __align__(16) unsigned short Bs[128 * 64];

    const int tid    = threadIdx.x;
    const int l      = tid & 63;
    const int wv     = tid >> 6;
    const int lane16 = l & 15;
    const int quad   = l >> 4;
    const int m0 = blockIdx.x * 128;
    const int n0 = blockIdx.y * 128;
    const int wm = (wv & 1) * 64;
    const int wn = (wv >> 1) * 64;

    f32x4 acc[4][4];
#pragma unroll
    for (int i = 0; i < 4; ++i)
#pragma unroll
        for (int j = 0; j < 4; ++j) acc[i][j] = f32x4{0.f, 0.f, 0.f, 0.f};

    for (int kt = 0; kt < K_DIM / 64; ++kt) {
        __syncthreads();
#pragma unroll
        for (int i = 0; i < 8; ++i) {
            int g    = i * 256 + tid;
            int row  = g >> 4;
            int grp  = g & 15;
            int c    = grp >> 1;
            int half = g & 1;
            int p    = c ^ (row & 7);
            int off  = row * 64 + p * 8 + half * 4;
            {
                float4 v = *(const float4*)(Af + (size_t)(m0 + row) * K_DIM + kt * 64 + grp * 4);
                ushort4 o;
                o.x = f2bf(v.x); o.y = f2bf(v.y); o.z = f2bf(v.z); o.w = f2bf(v.w);
                *(ushort4*)(As + off) = o;
            }
            {
                int4 v = *(const int4*)(Wi + (size_t)(n0 + row) * K_DIM + kt * 64 + grp * 4);
                ushort4 o;
                o.x = f2bf((float)v.x); o.y = f2bf((float)v.y);
                o.z = f2bf((float)v.z); o.w = f2bf((float)v.w);
                *(ushort4*)(Bs + off) = o;
            }
        }
        __syncthreads();

#pragma unroll
        for (int s = 0; s < 2; ++s) {
            bf16x8 af[4], bfr[4];
#pragma unroll
            for (int mt = 0; mt < 4; ++mt) {
                int row = wm + mt * 16 + lane16;
                int p   = (s * 4 + quad) ^ (row & 7);
                af[mt]  = *(const bf16x8*)(As + row * 64 + p * 8);
            }
#pragma unroll
            for (int nt = 0; nt < 4; ++nt) {
                int row = wn + nt * 16 + lane16;
                int p   = (s * 4 + quad) ^ (row & 7);
                bfr[nt] = *(const bf16x8*)(Bs + row * 64 + p * 8);
            }
#pragma unroll
            for (int mt = 0; mt < 4; ++mt)
#pragma unroll
                for (int nt = 0; nt < 4; ++nt)
                    acc[mt][nt] = __builtin_amdgcn_mfma_f32_16x16x32_bf16(
                        af[mt], bfr[nt], acc[mt][nt], 0, 0, 0);
        }
    }

#pragma unroll
    for (int nt = 0; nt < 4; ++nt) {
        int n    = n0 + wn + nt * 16 + lane16;
        float sc = w_scale[n];
        float bi = bias[n];
#pragma unroll
        for (int mt = 0; mt < 4; ++mt) {
#pragma unroll
            for (int r = 0; r < 4; ++r) {
                int m   = m0 + wm + mt * 16 + quad * 4 + r;
                float v = acc[mt][nt][r] * sc + bi;
                __builtin_nontemporal_store(
                    gelu_tanh_f(v), &out[(size_t)m * N_DIM + n]);
            }
        }
    }
}

extern "C" void kernel_launch(void* const* d_in, const int* in_sizes, int n_in,
                              void* d_out, int out_size, void* d_ws, size_t ws_size,
                              hipStream_t stream) {
    const float* hs   = (const float*)d_in[0];  // [8,2048,1152] fp32
    const int*   w8   = (const int*)d_in[1];    // [4608,1152] int32 (int8 values)
    const float* wsc  = (const float*)d_in[2];  // [4608]
    const float* bias = (const float*)d_in[3];  // [4608]
    float* out = (float*)d_out;                 // [8,2048,4608] fp32

    const size_t nA = (size_t)M_DIM * K_DIM;  // int8 elems
    const size_t nW = (size_t)N_DIM * K_DIM;
    const size_t need = nA + nW + (size_t)M_DIM * sizeof(float);

    dim3 grid(M_DIM / 128, N_DIM / 128);

    if (ws_size >= need) {
        signed char* qa = (signed char*)d_ws;
        signed char* qw = qa + nA;
        float* sA = (float*)(qa + nA + nW);  // 16B-aligned (nA+nW % 16 == 0)
        prepass<<<QA_BLOCKS + PW_BLOCKS, 256, 0, stream>>>(hs, w8, qa, sA, qw);
        qgelu_gemm_i8<<<grid, 256, 0, stream>>>(qa, qw, sA, wsc, bias, out);
    } else {
        qgelu_gemm_bf16_fused<<<grid, 256, 0, stream>>>(hs, w8, wsc, bias, out);
    }
}